// Round 4
// baseline (377.592 us; speedup 1.0000x reference)
//
#include <hip/hip_runtime.h>

typedef unsigned short u16;
typedef __attribute__((ext_vector_type(8))) __bf16 bf16x8;
typedef __attribute__((ext_vector_type(8))) unsigned short u16x8;
typedef __attribute__((ext_vector_type(4))) float f32x4;

__device__ __forceinline__ float bf2f(u16 h) {
    return __uint_as_float(((unsigned int)h) << 16);
}
__device__ __forceinline__ u16 f2bf(float f) {
    unsigned int u = __float_as_uint(f);
    u += 0x7fffu + ((u >> 16) & 1u);   // round-to-nearest-even
    return (u16)(u >> 16);
}
__device__ __forceinline__ bf16x8 zero_bf16x8() {
    union { unsigned int u[4]; bf16x8 v; } z;
    z.u[0] = z.u[1] = z.u[2] = z.u[3] = 0u;
    return z.v;
}
__device__ __forceinline__ void gload_lds16(const void* g, void* l) {
    __builtin_amdgcn_global_load_lds(
        (const __attribute__((address_space(1))) unsigned int*)g,
        (__attribute__((address_space(3))) unsigned int*)l, 16, 0, 0);
}
__device__ __forceinline__ void store_out(u16* p, float v)  { *p = f2bf(v); }
__device__ __forceinline__ void store_out(float* p, float v){ *p = v; }

// ================= fused pre-pass (1 launch) =================

__device__ __forceinline__ void do_cvt(
    const float* __restrict__ in, u16* __restrict__ out, int blk)
{
    int i = (blk * 256 + (int)threadIdx.x) * 8;
    float4 a = *(const float4*)(in + i);
    float4 b = *(const float4*)(in + i + 4);
    u16x8 o;
    o[0] = f2bf(a.x); o[1] = f2bf(a.y); o[2] = f2bf(a.z); o[3] = f2bf(a.w);
    o[4] = f2bf(b.x); o[5] = f2bf(b.y); o[6] = f2bf(b.z); o[7] = f2bf(b.w);
    *(u16x8*)(out + i) = o;
}

__device__ __forceinline__ void do_transpose(
    const float* __restrict__ in, u16* __restrict__ out, int K, int F, int t)
{
    __shared__ u16 tt[32][33];
    int fb = t % (F >> 5), kb = t / (F >> 5);
    int f0 = fb << 5, k0 = kb << 5;
    int lx = threadIdx.x & 31;
    int ly = threadIdx.x >> 5;
#pragma unroll
    for (int i = 0; i < 4; ++i) {
        int k = ly + i * 8;
        tt[k][lx] = f2bf(in[(size_t)(k0 + k) * F + f0 + lx]);
    }
    __syncthreads();
#pragma unroll
    for (int i = 0; i < 4; ++i) {
        int fy = ly + i * 8;
        out[(size_t)(f0 + fy) * K + k0 + lx] = tt[lx][fy];
    }
}

__device__ __forceinline__ void do_prep_d(
    const float* __restrict__ d, u16* __restrict__ o, int K, int blk)
{
    int i = blk * 256 + (int)threadIdx.x;
    int r = i & 7;
    int k = (i >> 3) % K;
    int t = i / (K * 8);
    o[i] = f2bf(d[((size_t)k * 8 + r) * 8 + t]);
}

__device__ __forceinline__ void do_prep_u(
    const float* __restrict__ u, u16* __restrict__ o, int F, int blk)
{
    int i = blk * 256 + (int)threadIdx.x;
    int r = i & 7;
    int f = (i >> 3) % F;
    int t = i / (F * 8);
    o[i] = f2bf(u[((size_t)r * F + f) * 8 + t] * 2.0f);
}

__global__ __launch_bounds__(256) void prep_all(
    const float* x, const float* k0, const float* k1, const float* k2,
    const float* d0, const float* d1, const float* d2,
    const float* u0, const float* u1, const float* u2,
    u16* xb, u16* k0T, u16* k1T, u16* k2T,
    u16* dS0, u16* dS1, u16* dS2, u16* uS0, u16* uS1, u16* uS2)
{
    int b = blockIdx.x;
    if      (b < 4096)  do_cvt(x, xb, b);
    else if (b < 6144)  do_transpose(k0, k0T, 1024, 2048, b - 4096);
    else if (b < 10240) do_transpose(k1, k1T, 2048, 2048, b - 6144);
    else if (b < 12288) do_transpose(k2, k2T, 2048, 1024, b - 10240);
    else if (b < 12544) do_prep_d(d0, dS0, 1024, b - 12288);
    else if (b < 13056) do_prep_d(d1, dS1, 2048, b - 12544);
    else if (b < 13568) do_prep_d(d2, dS2, 2048, b - 13056);
    else if (b < 14080) do_prep_u(u0, uS0, 2048, b - 13568);
    else if (b < 14592) do_prep_u(u1, uS1, 2048, b - 14080);
    else                do_prep_u(u2, uS2, 1024, b - 14592);
}

// ---------------- LoRA down-projection (unchanged) ----------------
__global__ __launch_bounds__(256) void lora_down(
    const u16* __restrict__ H, const u16* __restrict__ dS,
    u16* __restrict__ Aout, int K)
{
    int gt   = blockIdx.x * 256 + threadIdx.x;
    int row  = gt >> 3;
    int oct  = gt & 7;
    int task = row >> 10;
    const u16* hrow = H  + (size_t)row * K;
    const u16* dt   = dS + (size_t)task * K * 8;
    float acc[8];
#pragma unroll
    for (int r = 0; r < 8; ++r) acc[r] = 0.f;
    int kpt  = K >> 3;
    int kbeg = oct * kpt;
    for (int kk = kbeg; kk < kbeg + kpt; kk += 8) {
        u16x8 h8 = *(const u16x8*)(hrow + kk);
#pragma unroll
        for (int j = 0; j < 8; ++j) {
            float hv = bf2f(h8[j]);
            u16x8 dv = *(const u16x8*)(dt + (size_t)(kk + j) * 8);
#pragma unroll
            for (int r = 0; r < 8; ++r)
                acc[r] += hv * bf2f(dv[r]);
        }
    }
#pragma unroll
    for (int r = 0; r < 8; ++r) {
        acc[r] += __shfl_xor(acc[r], 1);
        acc[r] += __shfl_xor(acc[r], 2);
        acc[r] += __shfl_xor(acc[r], 4);
    }
    if (oct == 0) {
        u16x8 o;
#pragma unroll
        for (int r = 0; r < 8; ++r) o[r] = f2bf(acc[r]);
        *(u16x8*)(Aout + (size_t)row * 8) = o;
    }
}

// ============ 256x256 pipelined 8-phase GEMM + rank-8 LoRA epilogue ========
// Swizzle (R3, measured 0 conflicts): logical 16B chunk kc of row r at
// physical slot kc^(r&7). Stage: gload dest = linear tid*16 -> src kc =
// (tid&7)^(trow&7). Read: slot = (ks*4+lg)^(l15&7) -> 8 lanes/slot, min cyc.
//
// Pipelined schedule (NEW): phase p = { ds_read(quad p+1 operands, into the
// register set NOT used by this phase's MFMA) ; stage(slot p) ;
// lgkmcnt(n_p)=retire phase p-1 reads ; MFMA(quad p) ; [vmcnt] ; barrier }.
// MFMA overlaps the LDS pipe every phase; 8 barriers/iter (was 16).
// Quad sequence: buf0:(0,0)(0,1)(1,0)(1,1), buf1: same. Reg sets:
//   aFa: A-half for quads (0,*); aFb: (1,*); bF0: (*,0); bF1: (*,1).
// Reads at p target a set disjoint from MFMA(p)'s operands (verified table):
//   p0: rd bF1   | mfma aFa,bF0      p4: rd bF1   | mfma aFa,bF0
//   p1: rd aFb   | mfma aFa,bF1      p5: rd aFb   | mfma aFa,bF1
//   p2: rd --    | mfma aFb,bF0      p6: rd --    | mfma aFb,bF0
//   p3: rd aFa,bF0 | mfma aFb,bF1    p7: rd aFa,bF0(next t) | mfma aFb,bF1
// Stage slots (steady, tiles t0=2i buf0, t1=2i+1 buf1):
//   p0 buf1.A1<-t1  p1 buf1.B1<-t1  p2 buf0.A0<-t2  p3 buf0.B0<-t2
//   p4 buf0.A1<-t2  p5 buf0.B1<-t2  p6 buf1.A0<-t3  p7 buf1.B0<-t3
// Every slot's last ds_read-issue is >=2 phases before overwrite (>=1 full
// barrier after its lgkm-retire). vmcnt(2) at p2 (drains prev-p6,p7,p0,p1 ->
// buf1 tile ready for p3/p4/p5 reads) and p6 (drains p2..p5 -> buf0 ready
// for p7/p0'/p1' reads). lgkm counts: issue 4/8/0/12 per phase; wait(n_own)
// retires exactly the prior phase's reads.

#define LGKM0  do { asm volatile("s_waitcnt lgkmcnt(0)" ::: "memory"); \
                    __builtin_amdgcn_sched_barrier(0); } while (0)
#define LGKM4  do { asm volatile("s_waitcnt lgkmcnt(4)" ::: "memory"); \
                    __builtin_amdgcn_sched_barrier(0); } while (0)
#define LGKM8  do { asm volatile("s_waitcnt lgkmcnt(8)" ::: "memory"); \
                    __builtin_amdgcn_sched_barrier(0); } while (0)
#define LGKM12 do { asm volatile("s_waitcnt lgkmcnt(12)" ::: "memory"); \
                    __builtin_amdgcn_sched_barrier(0); } while (0)
#define VM2   asm volatile("s_waitcnt vmcnt(2)" ::: "memory")
#define VM4   asm volatile("s_waitcnt vmcnt(4)" ::: "memory")
#define VM0   asm volatile("s_waitcnt vmcnt(0)" ::: "memory")
#define SBAR  do { __builtin_amdgcn_sched_barrier(0); \
                   __builtin_amdgcn_s_barrier(); } while (0)
#define PRIO1 __builtin_amdgcn_s_setprio(1)
#define PRIO0 __builtin_amdgcn_s_setprio(0)

#define DS_A(dst, c, mh) do { \
    _Pragma("unroll") for (int mm = 0; mm < 4; ++mm) \
    _Pragma("unroll") for (int ks = 0; ks < 2; ++ks) \
        dst[mm][ks] = *(const bf16x8*)((const char*)&sA[c][0] + \
                       arowb + ((mh)*4+mm)*4096 + (ks ? cb1 : cb0)); } while (0)

#define DS_B(dst, c, nh) do { \
    _Pragma("unroll") for (int nn = 0; nn < 2; ++nn) \
    _Pragma("unroll") for (int ks = 0; ks < 2; ++ks) \
        dst[nn][ks] = *(const bf16x8*)((const char*)&sB[c][0] + \
                       browb + ((nh)*2+nn)*8192 + (ks ? cb1 : cb0)); } while (0)

#define MFMAQ(aset, bset, mh, nh) do { \
    _Pragma("unroll") for (int ks = 0; ks < 2; ++ks) \
    _Pragma("unroll") for (int mm = 0; mm < 4; ++mm) \
    _Pragma("unroll") for (int nn = 0; nn < 2; ++nn) \
        acc[(mh)*4+mm][(nh)*2+nn] = __builtin_amdgcn_mfma_f32_16x16x32_bf16( \
            aset[mm][ks], bset[nn][ks], acc[(mh)*4+mm][(nh)*2+nn], 0, 0, 0); } while (0)

#define STAGE_A(c, h, kt) do { \
    _Pragma("unroll") for (int s = 0; s < 2; ++s) \
        gload_lds16((const char*)A + (size_t)(unsigned)(aBase + \
                      ((h)*128 + s*64)*(K*2) + (kt)*128), \
                    (char*)&sA[c][0] + (h)*16384 + s*8192 + tdst); } while (0)

#define STAGE_B(c, h, kt) do { \
    _Pragma("unroll") for (int s = 0; s < 2; ++s) \
        gload_lds16((const char*)BT + (size_t)(unsigned)(bBase + \
                      ((h)*128 + s*64)*(K*2) + (kt)*128), \
                    (char*)&sB[c][0] + (h)*16384 + s*8192 + tdst); } while (0)

template<int RELU, typename OUT_T>
__global__ __launch_bounds__(512, 2) void gemm_lora8(
    const u16* __restrict__ A, const u16* __restrict__ BT,
    const u16* __restrict__ ALR, const u16* __restrict__ US,
    const float* __restrict__ bias, OUT_T* __restrict__ C,
    int N, int K)
{
    __shared__ __align__(16) u16 sA[2][256 * 64];
    __shared__ __align__(16) u16 sB[2][256 * 64];

    const int tid  = threadIdx.x;
    const int lane = tid & 63;
    const int wave = tid >> 6;
    const int wr   = wave >> 2;   // 0..1
    const int wc   = wave & 3;    // 0..3
    const int l15  = lane & 15;
    const int lg   = lane >> 4;

    // bijective XCD swizzle (m204)
    const int nwg = gridDim.x;
    const int orig = blockIdx.x;
    const int q = nwg >> 3, r = nwg & 7;
    const int x = orig & 7, o = orig >> 3;
    const int wg = (x < r ? x * (q + 1) : r * (q + 1) + (x - r) * q) + o;
    const int nbn  = N >> 8;
    const int bm   = wg / nbn;
    const int bn   = wg % nbn;
    const int brow = bm << 8;
    const int bcol = bn << 8;
    const int task = brow >> 10;

    // staging addressing (kc independent of h,s since h*128,s*64 == 0 mod 8)
    const int trow = tid >> 3;                       // 0..63
    const int tkc  = (tid & 7) ^ (trow & 7);
    const int tdst = tid * 16;
    const int aBase = (brow + trow) * (K * 2) + tkc * 16;
    const int bBase = (bcol + trow) * (K * 2) + tkc * 16;

    // ds_read column bases: slot = (ks*4+lg) ^ (l15&7)
    const int rp    = l15 & 7;
    const int cb0   = ((lg ^ (rp & 3)) << 4) | ((rp & 4) << 4);  // ks=0
    const int cb1   = cb0 ^ 64;                                   // ks=1
    const int arowb = (wr * 16 + l15) * 128;
    const int browb = (wc * 16 + l15) * 128;

    f32x4 acc[8][4];
    const f32x4 zf = {0.f, 0.f, 0.f, 0.f};
#pragma unroll
    for (int m = 0; m < 8; ++m)
#pragma unroll
        for (int n = 0; n < 4; ++n) acc[m][n] = zf;

    bf16x8 aFa[4][2], aFb[4][2], bF0[2][2], bF1[2][2];

    // prologue: buf0 <- t0 (4 halves), buf1 <- t1 A0,B0; then preload Q0 frags
    STAGE_A(0, 0, 0); STAGE_B(0, 0, 0); STAGE_A(0, 1, 0); STAGE_B(0, 1, 0);
    STAGE_A(1, 0, 1); STAGE_B(1, 0, 1);
    VM4;                 // t0's 8 loads landed; buf1 A0,B0 in flight
    SBAR;
    DS_A(aFa, 0, 0); DS_B(bF0, 0, 0);   // 12 reads; retired by p0's LGKM4

    const int iters = K >> 7;
#pragma unroll 1
    for (int i = 0; i < iters - 1; ++i) {
        const int t1 = 2 * i + 1, t2 = 2 * i + 2, t3 = 2 * i + 3;
        // p0
        DS_B(bF1, 0, 1);
        STAGE_A(1, 1, t1);
        LGKM4;  PRIO1; MFMAQ(aFa, bF0, 0, 0); PRIO0; SBAR;
        // p1
        DS_A(aFb, 0, 1);
        STAGE_B(1, 1, t1);
        LGKM8;  PRIO1; MFMAQ(aFa, bF1, 0, 1); PRIO0; SBAR;
        // p2
        STAGE_A(0, 0, t2);
        LGKM0;  PRIO1; MFMAQ(aFb, bF0, 1, 0); PRIO0;
        VM2; SBAR;
        // p3
        DS_A(aFa, 1, 0); DS_B(bF0, 1, 0);
        STAGE_B(0, 0, t2);
        LGKM12; PRIO1; MFMAQ(aFb, bF1, 1, 1); PRIO0; SBAR;
        // p4
        DS_B(bF1, 1, 1);
        STAGE_A(0, 1, t2);
        LGKM4;  PRIO1; MFMAQ(aFa, bF0, 0, 0); PRIO0; SBAR;
        // p5
        DS_A(aFb, 1, 1);
        STAGE_B(0, 1, t2);
        LGKM8;  PRIO1; MFMAQ(aFa, bF1, 0, 1); PRIO0; SBAR;
        // p6
        STAGE_A(1, 0, t3);
        LGKM0;  PRIO1; MFMAQ(aFb, bF0, 1, 0); PRIO0;
        VM2; SBAR;
        // p7
        DS_A(aFa, 0, 0); DS_B(bF0, 0, 0);
        STAGE_B(1, 0, t3);
        LGKM12; PRIO1; MFMAQ(aFb, bF1, 1, 1); PRIO0; SBAR;
    }

    // tail iteration (no further stages; drain)
    {
        const int t1 = 2 * iters - 1;
        // p0
        DS_B(bF1, 0, 1);
        STAGE_A(1, 1, t1);
        LGKM4;  PRIO1; MFMAQ(aFa, bF0, 0, 0); PRIO0; SBAR;
        // p1
        DS_A(aFb, 0, 1);
        STAGE_B(1, 1, t1);
        LGKM8;  PRIO1; MFMAQ(aFa, bF1, 0, 1); PRIO0; SBAR;
        // p2
        LGKM0;  PRIO1; MFMAQ(aFb, bF0, 1, 0); PRIO0;
        VM0; SBAR;
        // p3
        DS_A(aFa, 1, 0); DS_B(bF0, 1, 0);
        LGKM12; PRIO1; MFMAQ(aFb, bF1, 1, 1); PRIO0; SBAR;
        // p4
        DS_B(bF1, 1, 1);
        LGKM4;  PRIO1; MFMAQ(aFa, bF0, 0, 0); PRIO0; SBAR;
        // p5
        DS_A(aFb, 1, 1);
        LGKM8;  PRIO1; MFMAQ(aFa, bF1, 0, 1); PRIO0; SBAR;
        // p6
        LGKM0;  PRIO1; MFMAQ(aFb, bF0, 1, 0); PRIO0; SBAR;
        // p7
        LGKM0;  PRIO1; MFMAQ(aFb, bF1, 1, 1); PRIO0;
    }

    // rank-8 LoRA delta: one extra MFMA round (k 0..7 valid, lanes lg>0 zero)
    bf16x8 z8 = zero_bf16x8();
    bf16x8 bU[4];
#pragma unroll
    for (int n = 0; n < 4; ++n) {
        int col = bcol + n * 64 + wc * 16 + l15;
        bU[n] = (lg == 0) ? *(const bf16x8*)(US + ((size_t)task * N + col) * 8) : z8;
    }
#pragma unroll
    for (int m = 0; m < 8; ++m) {
        int row = brow + m * 32 + wr * 16 + l15;
        bf16x8 aL = (lg == 0) ? *(const bf16x8*)(ALR + (size_t)row * 8) : z8;
#pragma unroll
        for (int n = 0; n < 4; ++n)
            acc[m][n] = __builtin_amdgcn_mfma_f32_16x16x32_bf16(
                aL, bU[n], acc[m][n], 0, 0, 0);
    }

    // bias (+ReLU) + store; C/D: col = lane&15, row = lg*4 + reg
#pragma unroll
    for (int n = 0; n < 4; ++n) {
        int col  = bcol + n * 64 + wc * 16 + l15;
        float bv = bias[col];
#pragma unroll
        for (int m = 0; m < 8; ++m) {
            int row0 = brow + m * 32 + wr * 16 + lg * 4;
#pragma unroll
            for (int rr = 0; rr < 4; ++rr) {
                float v = acc[m][n][rr] + bv;
                if (RELU) v = fmaxf(v, 0.0f);
                store_out(&C[(size_t)(row0 + rr) * N + col], v);
            }
        }
    }
}

// ---------------- launch ----------------

extern "C" void kernel_launch(void* const* d_in, const int* in_sizes, int n_in,
                              void* d_out, int out_size, void* d_ws, size_t ws_size,
                              hipStream_t stream) {
    const float* x  = (const float*)d_in[0];
    const float* k0 = (const float*)d_in[1];
    const float* b0 = (const float*)d_in[2];
    const float* d0 = (const float*)d_in[3];
    const float* u0 = (const float*)d_in[4];
    const float* k1 = (const float*)d_in[5];
    const float* b1 = (const float*)d_in[6];
    const float* d1 = (const float*)d_in[7];
    const float* u1 = (const float*)d_in[8];
    const float* k2 = (const float*)d_in[9];
    const float* b2 = (const float*)d_in[10];
    const float* d2 = (const float*)d_in[11];
    const float* u2 = (const float*)d_in[12];

    const int T = 8, B = 1024, D = 1024, H1 = 2048, H2 = 2048, H3 = 1024;
    const int M = T * B;

    u16* w = (u16*)d_ws;
    size_t off = 0;
    u16* xb  = w + off; off += (size_t)M * D;
    u16* k0T = w + off; off += (size_t)H1 * D;
    u16* k1T = w + off; off += (size_t)H2 * H1;
    u16* k2T = w + off; off += (size_t)H3 * H2;
    u16* dS0 = w + off; off += (size_t)T * D * 8;
    u16* dS1 = w + off; off += (size_t)T * H1 * 8;
    u16* dS2 = w + off; off += (size_t)T * H2 * 8;
    u16* uS0 = w + off; off += (size_t)T * H1 * 8;
    u16* uS1 = w + off; off += (size_t)T * H2 * 8;
    u16* uS2 = w + off; off += (size_t)T * H3 * 8;
    u16* h1  = w + off; off += (size_t)M * H1;
    u16* h2  = w + off; off += (size_t)M * H2;
    u16* Ab  = w + off; off += (size_t)M * 8;
    (void)ws_size; (void)in_sizes; (void)n_in; (void)out_size;

    prep_all<<<14848, 256, 0, stream>>>(
        x, k0, k1, k2, d0, d1, d2, u0, u1, u2,
        xb, k0T, k1T, k2T, dS0, dS1, dS2, uS0, uS1, uS2);

    // layer 0
    lora_down<<<(M * 8) / 256, 256, 0, stream>>>(xb, dS0, Ab, D);
    gemm_lora8<1, u16><<<(M / 256) * (H1 / 256), 512, 0, stream>>>(
        xb, k0T, Ab, uS0, b0, h1, H1, D);
    // layer 1
    lora_down<<<(M * 8) / 256, 256, 0, stream>>>(h1, dS1, Ab, H1);
    gemm_lora8<1, u16><<<(M / 256) * (H2 / 256), 512, 0, stream>>>(
        h1, k1T, Ab, uS1, b1, h2, H2, H1);
    // layer 2 (no relu, fp32 out)
    lora_down<<<(M * 8) / 256, 256, 0, stream>>>(h2, dS2, Ab, H2);
    gemm_lora8<0, float><<<(M / 256) * (H3 / 256), 512, 0, stream>>>(
        h2, k2T, Ab, uS2, b2, (float*)d_out, H3, H2);
}

// Round 5
// 280.148 us; speedup vs baseline: 1.3478x; 1.3478x over previous
//
#include <hip/hip_runtime.h>

typedef unsigned short u16;
typedef __attribute__((ext_vector_type(8))) __bf16 bf16x8;
typedef __attribute__((ext_vector_type(8))) unsigned short u16x8;
typedef __attribute__((ext_vector_type(4))) float f32x4;

__device__ __forceinline__ float bf2f(u16 h) {
    return __uint_as_float(((unsigned int)h) << 16);
}
__device__ __forceinline__ u16 f2bf(float f) {
    unsigned int u = __float_as_uint(f);
    u += 0x7fffu + ((u >> 16) & 1u);   // round-to-nearest-even
    return (u16)(u >> 16);
}
__device__ __forceinline__ bf16x8 zero_bf16x8() {
    union { unsigned int u[4]; bf16x8 v; } z;
    z.u[0] = z.u[1] = z.u[2] = z.u[3] = 0u;
    return z.v;
}
__device__ __forceinline__ void gload_lds16(const void* g, void* l) {
    __builtin_amdgcn_global_load_lds(
        (const __attribute__((address_space(1))) unsigned int*)g,
        (__attribute__((address_space(3))) unsigned int*)l, 16, 0, 0);
}
__device__ __forceinline__ void store_out(u16* p, float v)  { *p = f2bf(v); }
__device__ __forceinline__ void store_out(float* p, float v){ *p = v; }

// ================= fused pre-pass (1 launch) =================

__device__ __forceinline__ void do_cvt(
    const float* __restrict__ in, u16* __restrict__ out, int blk)
{
    int i = (blk * 256 + (int)threadIdx.x) * 8;
    float4 a = *(const float4*)(in + i);
    float4 b = *(const float4*)(in + i + 4);
    u16x8 o;
    o[0] = f2bf(a.x); o[1] = f2bf(a.y); o[2] = f2bf(a.z); o[3] = f2bf(a.w);
    o[4] = f2bf(b.x); o[5] = f2bf(b.y); o[6] = f2bf(b.z); o[7] = f2bf(b.w);
    *(u16x8*)(out + i) = o;
}

__device__ __forceinline__ void do_transpose(
    const float* __restrict__ in, u16* __restrict__ out, int K, int F, int t)
{
    __shared__ u16 tt[32][33];
    int fb = t % (F >> 5), kb = t / (F >> 5);
    int f0 = fb << 5, k0 = kb << 5;
    int lx = threadIdx.x & 31;
    int ly = threadIdx.x >> 5;
#pragma unroll
    for (int i = 0; i < 4; ++i) {
        int k = ly + i * 8;
        tt[k][lx] = f2bf(in[(size_t)(k0 + k) * F + f0 + lx]);
    }
    __syncthreads();
#pragma unroll
    for (int i = 0; i < 4; ++i) {
        int fy = ly + i * 8;
        out[(size_t)(f0 + fy) * K + k0 + lx] = tt[lx][fy];
    }
}

__device__ __forceinline__ void do_prep_d(
    const float* __restrict__ d, u16* __restrict__ o, int K, int blk)
{
    int i = blk * 256 + (int)threadIdx.x;
    int r = i & 7;
    int k = (i >> 3) % K;
    int t = i / (K * 8);
    o[i] = f2bf(d[((size_t)k * 8 + r) * 8 + t]);
}

__device__ __forceinline__ void do_prep_u(
    const float* __restrict__ u, u16* __restrict__ o, int F, int blk)
{
    int i = blk * 256 + (int)threadIdx.x;
    int r = i & 7;
    int f = (i >> 3) % F;
    int t = i / (F * 8);
    o[i] = f2bf(u[((size_t)r * F + f) * 8 + t] * 2.0f);
}

__global__ __launch_bounds__(256) void prep_all(
    const float* x, const float* k0, const float* k1, const float* k2,
    const float* d0, const float* d1, const float* d2,
    const float* u0, const float* u1, const float* u2,
    u16* xb, u16* k0T, u16* k1T, u16* k2T,
    u16* dS0, u16* dS1, u16* dS2, u16* uS0, u16* uS1, u16* uS2)
{
    int b = blockIdx.x;
    if      (b < 4096)  do_cvt(x, xb, b);
    else if (b < 6144)  do_transpose(k0, k0T, 1024, 2048, b - 4096);
    else if (b < 10240) do_transpose(k1, k1T, 2048, 2048, b - 6144);
    else if (b < 12288) do_transpose(k2, k2T, 2048, 1024, b - 10240);
    else if (b < 12544) do_prep_d(d0, dS0, 1024, b - 12288);
    else if (b < 13056) do_prep_d(d1, dS1, 2048, b - 12544);
    else if (b < 13568) do_prep_d(d2, dS2, 2048, b - 13056);
    else if (b < 14080) do_prep_u(u0, uS0, 2048, b - 13568);
    else if (b < 14592) do_prep_u(u1, uS1, 2048, b - 14080);
    else                do_prep_u(u2, uS2, 1024, b - 14592);
}

// ---------------- LoRA down-projection (unchanged) ----------------
__global__ __launch_bounds__(256) void lora_down(
    const u16* __restrict__ H, const u16* __restrict__ dS,
    u16* __restrict__ Aout, int K)
{
    int gt   = blockIdx.x * 256 + threadIdx.x;
    int row  = gt >> 3;
    int oct  = gt & 7;
    int task = row >> 10;
    const u16* hrow = H  + (size_t)row * K;
    const u16* dt   = dS + (size_t)task * K * 8;
    float acc[8];
#pragma unroll
    for (int r = 0; r < 8; ++r) acc[r] = 0.f;
    int kpt  = K >> 3;
    int kbeg = oct * kpt;
    for (int kk = kbeg; kk < kbeg + kpt; kk += 8) {
        u16x8 h8 = *(const u16x8*)(hrow + kk);
#pragma unroll
        for (int j = 0; j < 8; ++j) {
            float hv = bf2f(h8[j]);
            u16x8 dv = *(const u16x8*)(dt + (size_t)(kk + j) * 8);
#pragma unroll
            for (int r = 0; r < 8; ++r)
                acc[r] += hv * bf2f(dv[r]);
        }
    }
#pragma unroll
    for (int r = 0; r < 8; ++r) {
        acc[r] += __shfl_xor(acc[r], 1);
        acc[r] += __shfl_xor(acc[r], 2);
        acc[r] += __shfl_xor(acc[r], 4);
    }
    if (oct == 0) {
        u16x8 o;
#pragma unroll
        for (int r = 0; r < 8; ++r) o[r] = f2bf(acc[r]);
        *(u16x8*)(Aout + (size_t)row * 8) = o;
    }
}

// ============ 256xBN 8-phase GEMM + rank-8 LoRA epilogue ==================
// R3 schedule (proven: 0 bank conflicts, no spill), templated on BN (256/128).
// Swizzle: logical 16B chunk kc of row r at physical slot kc^(r&7); stage via
// pre-swizzled global source (rule 21); read slot = (ks*4+lg)^(l15&7) ->
// 8 lanes/slot = conflict-free (measured 0 in R3).
// Per phase: { ds_read own frags ; stage 1 half ; barrier ; lgkm(0) ;
// MFMA quadrant ; [counted vmcnt at P3/P7] ; barrier }.
// vmcnt arithmetic: per-phase stage sizes alternate A-half (2 loads) and
// B-half (SBL loads). At P3/P7 the allowed in-flight = stages of the 2
// youngest phases = 2+SBL -> vmcnt(4) for BN=256, vmcnt(3) for BN=128.
// Prologue stages 3 halves-pairs (buf0 full + buf1 A0,B0 = 3*(2+SBL) loads);
// wait to (2+SBL) retires exactly buf0's tile.

#define WAIT_LGKM0 do { asm volatile("s_waitcnt lgkmcnt(0)" ::: "memory"); \
                        __builtin_amdgcn_sched_barrier(0); } while (0)
#define WVMC do { if constexpr (BN == 256) { \
                    asm volatile("s_waitcnt vmcnt(4)" ::: "memory"); \
                  } else { \
                    asm volatile("s_waitcnt vmcnt(3)" ::: "memory"); } } while (0)
#define WVM0  asm volatile("s_waitcnt vmcnt(0)" ::: "memory")
#define BARRIER   asm volatile("s_barrier" ::: "memory")
#define PRIO1     __builtin_amdgcn_s_setprio(1)
#define PRIO0     __builtin_amdgcn_s_setprio(0)

#define DS_A(c, mh) do { \
    _Pragma("unroll") for (int mm = 0; mm < 4; ++mm) \
    _Pragma("unroll") for (int ks = 0; ks < 2; ++ks) \
        aF[mm][ks] = *(const bf16x8*)((const char*)&sA[c][0] + \
                       arowb + ((mh)*4+mm)*4096 + (ks ? cb1 : cb0)); } while (0)

#define DS_B(c, nh, bset) do { \
    _Pragma("unroll") for (int nn = 0; nn < NBH; ++nn) \
    _Pragma("unroll") for (int ks = 0; ks < 2; ++ks) \
        bset[nn][ks] = *(const bf16x8*)((const char*)&sB[c][0] + \
                       browb + ((nh)*NBH+nn)*8192 + (ks ? cb1 : cb0)); } while (0)

#define MFMAQ(mh, nh, bset) do { \
    _Pragma("unroll") for (int ks = 0; ks < 2; ++ks) \
    _Pragma("unroll") for (int mm = 0; mm < 4; ++mm) \
    _Pragma("unroll") for (int nn = 0; nn < NBH; ++nn) \
        acc[(mh)*4+mm][(nh)*NBH+nn] = __builtin_amdgcn_mfma_f32_16x16x32_bf16( \
            aF[mm][ks], bset[nn][ks], acc[(mh)*4+mm][(nh)*NBH+nn], 0, 0, 0); } while (0)

#define STAGE_A(c, h, kt) do { \
    _Pragma("unroll") for (int s = 0; s < 2; ++s) \
        gload_lds16((const char*)A + (size_t)(unsigned)(aBase + \
                      ((h)*128 + s*64)*(K*2) + (kt)*128), \
                    (char*)&sA[c][0] + (h)*16384 + s*8192 + tdst); } while (0)

#define STAGE_B(c, h, kt) do { \
    _Pragma("unroll") for (int s = 0; s < SBL; ++s) \
        gload_lds16((const char*)BT + (size_t)(unsigned)(bBase + \
                      ((h)*BNH + s*64)*(K*2) + (kt)*128), \
                    (char*)&sB[c][0] + (h)*(BNH*128) + s*8192 + tdst); } while (0)

template<int RELU, int BN, typename OUT_T>
__global__ __launch_bounds__(512, 2) void gemm_lora8(
    const u16* __restrict__ A, const u16* __restrict__ BT,
    const u16* __restrict__ ALR, const u16* __restrict__ US,
    const float* __restrict__ bias, OUT_T* __restrict__ C,
    int N, int K)
{
    constexpr int SBL = BN / 128;   // stage loads/thread per B-half
    constexpr int NBH = BN / 128;   // 16-col blocks per wave per B-half
    constexpr int NBN = BN / 64;    // 16-col blocks per wave total
    constexpr int BNH = BN / 2;     // rows per B-half

    __shared__ __align__(16) u16 sA[2][256 * 64];
    __shared__ __align__(16) u16 sB[2][BN * 64];

    const int tid  = threadIdx.x;
    const int lane = tid & 63;
    const int wave = tid >> 6;
    const int wr   = wave >> 2;   // 0..1
    const int wc   = wave & 3;    // 0..3
    const int l15  = lane & 15;
    const int lg   = lane >> 4;

    // bijective XCD swizzle (m204)
    const int nwg = gridDim.x;
    const int orig = blockIdx.x;
    const int q = nwg >> 3, r = nwg & 7;
    const int x = orig & 7, o = orig >> 3;
    const int wg = (x < r ? x * (q + 1) : r * (q + 1) + (x - r) * q) + o;
    const int nbn  = N / BN;
    const int bm   = wg / nbn;
    const int bn   = wg % nbn;
    const int brow = bm << 8;
    const int bcol = bn * BN;
    const int task = brow >> 10;

    // staging addressing (kc independent of h,s since half offsets are 0 mod 8)
    const int trow = tid >> 3;                       // 0..63
    const int tkc  = (tid & 7) ^ (trow & 7);
    const int tdst = tid * 16;
    const int aBase = (brow + trow) * (K * 2) + tkc * 16;
    const int bBase = (bcol + trow) * (K * 2) + tkc * 16;

    // ds_read column bases: slot = (ks*4+lg) ^ (l15&7)
    const int rp    = l15 & 7;
    const int cb0   = ((lg ^ (rp & 3)) << 4) | ((rp & 4) << 4);  // ks=0
    const int cb1   = cb0 ^ 64;                                   // ks=1
    const int arowb = (wr * 16 + l15) * 128;
    const int browb = (wc * 16 + l15) * 128;

    f32x4 acc[8][NBN];
    const f32x4 zf = {0.f, 0.f, 0.f, 0.f};
#pragma unroll
    for (int m = 0; m < 8; ++m)
#pragma unroll
        for (int n = 0; n < NBN; ++n) acc[m][n] = zf;

    bf16x8 aF[4][2], bF0[NBH][2], bF1[NBH][2];

    // prologue: buf0 <- t0 (4 halves), buf1 <- t1 A0,B0
    STAGE_A(0, 0, 0); STAGE_B(0, 0, 0); STAGE_A(0, 1, 0); STAGE_B(0, 1, 0);
    STAGE_A(1, 0, 1); STAGE_B(1, 0, 1);
    WVMC;              // buf0 tile landed; buf1 A0,B0 in flight
    BARRIER;

    const int iters = K >> 7;
#pragma unroll 1
    for (int i = 0; i < iters; ++i) {
        const int t1 = 2 * i + 1, t2 = 2 * i + 2, t3 = 2 * i + 3;
        const bool nl = (i + 1 < iters);

        // P0: quad(0,0) buf0 ; stage buf1.A1 <- t1
        DS_A(0, 0); DS_B(0, 0, bF0);
        STAGE_A(1, 1, t1);
        BARRIER; WAIT_LGKM0;
        PRIO1; MFMAQ(0, 0, bF0); PRIO0;
        BARRIER;
        // P1: quad(0,1) buf0 ; stage buf1.B1 <- t1
        DS_B(0, 1, bF1);
        STAGE_B(1, 1, t1);
        BARRIER; WAIT_LGKM0;
        PRIO1; MFMAQ(0, 1, bF1); PRIO0;
        BARRIER;
        // P2: quad(1,0) buf0 ; stage buf0.A0 <- t2
        DS_A(0, 1);
        if (nl) STAGE_A(0, 0, t2);
        BARRIER; WAIT_LGKM0;
        PRIO1; MFMAQ(1, 0, bF0); PRIO0;
        BARRIER;
        // P3: quad(1,1) buf0 ; stage buf0.B0 <- t2 ; counted vmcnt
        if (nl) STAGE_B(0, 0, t2);
        BARRIER; WAIT_LGKM0;
        PRIO1; MFMAQ(1, 1, bF1); PRIO0;
        if (nl) { WVMC; } else { WVM0; }
        BARRIER;
        // P4: quad(0,0) buf1 ; stage buf0.A1 <- t2
        DS_A(1, 0); DS_B(1, 0, bF0);
        if (nl) STAGE_A(0, 1, t2);
        BARRIER; WAIT_LGKM0;
        PRIO1; MFMAQ(0, 0, bF0); PRIO0;
        BARRIER;
        // P5: quad(0,1) buf1 ; stage buf0.B1 <- t2
        DS_B(1, 1, bF1);
        if (nl) STAGE_B(0, 1, t2);
        BARRIER; WAIT_LGKM0;
        PRIO1; MFMAQ(0, 1, bF1); PRIO0;
        BARRIER;
        // P6: quad(1,0) buf1 ; stage buf1.A0 <- t3
        DS_A(1, 1);
        if (nl) STAGE_A(1, 0, t3);
        BARRIER; WAIT_LGKM0;
        PRIO1; MFMAQ(1, 0, bF0); PRIO0;
        BARRIER;
        // P7: quad(1,1) buf1 ; stage buf1.B0 <- t3 ; counted vmcnt
        if (nl) STAGE_B(1, 0, t3);
        BARRIER; WAIT_LGKM0;
        PRIO1; MFMAQ(1, 1, bF1); PRIO0;
        if (nl) { WVMC; } else { WVM0; }
        BARRIER;
    }

    // rank-8 LoRA delta: one extra MFMA round (k 0..7 valid, lanes lg>0 zero)
    bf16x8 z8 = zero_bf16x8();
    bf16x8 bU[NBN];
#pragma unroll
    for (int n = 0; n < NBN; ++n) {
        int col = bcol + n * 64 + wc * 16 + l15;
        bU[n] = (lg == 0) ? *(const bf16x8*)(US + ((size_t)task * N + col) * 8) : z8;
    }
#pragma unroll
    for (int m = 0; m < 8; ++m) {
        int row = brow + m * 32 + wr * 16 + l15;
        bf16x8 aL = (lg == 0) ? *(const bf16x8*)(ALR + (size_t)row * 8) : z8;
#pragma unroll
        for (int n = 0; n < NBN; ++n)
            acc[m][n] = __builtin_amdgcn_mfma_f32_16x16x32_bf16(
                aL, bU[n], acc[m][n], 0, 0, 0);
    }

    // bias (+ReLU) + store; C/D: col = lane&15, row = lg*4 + reg
#pragma unroll
    for (int n = 0; n < NBN; ++n) {
        int col  = bcol + n * 64 + wc * 16 + l15;
        float bv = bias[col];
#pragma unroll
        for (int m = 0; m < 8; ++m) {
            int row0 = brow + m * 32 + wr * 16 + lg * 4;
#pragma unroll
            for (int rr = 0; rr < 4; ++rr) {
                float v = acc[m][n][rr] + bv;
                if (RELU) v = fmaxf(v, 0.0f);
                store_out(&C[(size_t)(row0 + rr) * N + col], v);
            }
        }
    }
}

// ---------------- launch ----------------

extern "C" void kernel_launch(void* const* d_in, const int* in_sizes, int n_in,
                              void* d_out, int out_size, void* d_ws, size_t ws_size,
                              hipStream_t stream) {
    const float* x  = (const float*)d_in[0];
    const float* k0 = (const float*)d_in[1];
    const float* b0 = (const float*)d_in[2];
    const float* d0 = (const float*)d_in[3];
    const float* u0 = (const float*)d_in[4];
    const float* k1 = (const float*)d_in[5];
    const float* b1 = (const float*)d_in[6];
    const float* d1 = (const float*)d_in[7];
    const float* u1 = (const float*)d_in[8];
    const float* k2 = (const float*)d_in[9];
    const float* b2 = (const float*)d_in[10];
    const float* d2 = (const float*)d_in[11];
    const float* u2 = (const float*)d_in[12];

    const int T = 8, B = 1024, D = 1024, H1 = 2048, H2 = 2048, H3 = 1024;
    const int M = T * B;

    u16* w = (u16*)d_ws;
    size_t off = 0;
    u16* xb  = w + off; off += (size_t)M * D;
    u16* k0T = w + off; off += (size_t)H1 * D;
    u16* k1T = w + off; off += (size_t)H2 * H1;
    u16* k2T = w + off; off += (size_t)H3 * H2;
    u16* dS0 = w + off; off += (size_t)T * D * 8;
    u16* dS1 = w + off; off += (size_t)T * H1 * 8;
    u16* dS2 = w + off; off += (size_t)T * H2 * 8;
    u16* uS0 = w + off; off += (size_t)T * H1 * 8;
    u16* uS1 = w + off; off += (size_t)T * H2 * 8;
    u16* uS2 = w + off; off += (size_t)T * H3 * 8;
    u16* h1  = w + off; off += (size_t)M * H1;
    u16* h2  = w + off; off += (size_t)M * H2;
    u16* Ab  = w + off; off += (size_t)M * 8;
    (void)ws_size; (void)in_sizes; (void)n_in; (void)out_size;

    prep_all<<<14848, 256, 0, stream>>>(
        x, k0, k1, k2, d0, d1, d2, u0, u1, u2,
        xb, k0T, k1T, k2T, dS0, dS1, dS2, uS0, uS1, uS2);

    // layer 0 (BN=256: 32x8 = 256 blocks)
    lora_down<<<(M * 8) / 256, 256, 0, stream>>>(xb, dS0, Ab, D);
    gemm_lora8<1, 256, u16><<<(M / 256) * (H1 / 256), 512, 0, stream>>>(
        xb, k0T, Ab, uS0, b0, h1, H1, D);
    // layer 1 (BN=256: 32x8 = 256 blocks)
    lora_down<<<(M * 8) / 256, 256, 0, stream>>>(h1, dS1, Ab, H1);
    gemm_lora8<1, 256, u16><<<(M / 256) * (H2 / 256), 512, 0, stream>>>(
        h1, k1T, Ab, uS1, b1, h2, H2, H1);
    // layer 2 (no relu, fp32 out; BN=128: 32x8 = 256 blocks, full grid)
    lora_down<<<(M * 8) / 256, 256, 0, stream>>>(h2, dS2, Ab, H2);
    gemm_lora8<0, 128, float><<<(M / 256) * (H3 / 128), 512, 0, stream>>>(
        h2, k2T, Ab, uS2, b2, (float*)d_out, H3, H2);
}

// Round 6
// 261.537 us; speedup vs baseline: 1.4437x; 1.0712x over previous
//
#include <hip/hip_runtime.h>

typedef unsigned short u16;
typedef __attribute__((ext_vector_type(8))) __bf16 bf16x8;
typedef __attribute__((ext_vector_type(8))) unsigned short u16x8;
typedef __attribute__((ext_vector_type(4))) float f32x4;

__device__ __forceinline__ float bf2f(u16 h) {
    return __uint_as_float(((unsigned int)h) << 16);
}
__device__ __forceinline__ u16 f2bf(float f) {
    unsigned int u = __float_as_uint(f);
    u += 0x7fffu + ((u >> 16) & 1u);   // round-to-nearest-even
    return (u16)(u >> 16);
}
__device__ __forceinline__ bf16x8 zero_bf16x8() {
    union { unsigned int u[4]; bf16x8 v; } z;
    z.u[0] = z.u[1] = z.u[2] = z.u[3] = 0u;
    return z.v;
}
__device__ __forceinline__ void gload_lds16(const void* g, void* l) {
    __builtin_amdgcn_global_load_lds(
        (const __attribute__((address_space(1))) unsigned int*)g,
        (__attribute__((address_space(3))) unsigned int*)l, 16, 0, 0);
}
__device__ __forceinline__ void store_out(u16* p, float v)  { *p = f2bf(v); }
__device__ __forceinline__ void store_out(float* p, float v){ *p = v; }

// ================= fused pre-pass (1 launch) =================

__device__ __forceinline__ void do_cvt(
    const float* __restrict__ in, u16* __restrict__ out, int blk)
{
    int i = (blk * 256 + (int)threadIdx.x) * 8;
    float4 a = *(const float4*)(in + i);
    float4 b = *(const float4*)(in + i + 4);
    u16x8 o;
    o[0] = f2bf(a.x); o[1] = f2bf(a.y); o[2] = f2bf(a.z); o[3] = f2bf(a.w);
    o[4] = f2bf(b.x); o[5] = f2bf(b.y); o[6] = f2bf(b.z); o[7] = f2bf(b.w);
    *(u16x8*)(out + i) = o;
}

__device__ __forceinline__ void do_transpose(
    const float* __restrict__ in, u16* __restrict__ out, int K, int F, int t)
{
    __shared__ u16 tt[32][33];
    int fb = t % (F >> 5), kb = t / (F >> 5);
    int f0 = fb << 5, k0 = kb << 5;
    int lx = threadIdx.x & 31;
    int ly = threadIdx.x >> 5;
#pragma unroll
    for (int i = 0; i < 4; ++i) {
        int k = ly + i * 8;
        tt[k][lx] = f2bf(in[(size_t)(k0 + k) * F + f0 + lx]);
    }
    __syncthreads();
#pragma unroll
    for (int i = 0; i < 4; ++i) {
        int fy = ly + i * 8;
        out[(size_t)(f0 + fy) * K + k0 + lx] = tt[lx][fy];
    }
}

__device__ __forceinline__ void do_prep_d(
    const float* __restrict__ d, u16* __restrict__ o, int K, int blk)
{
    int i = blk * 256 + (int)threadIdx.x;
    int r = i & 7;
    int k = (i >> 3) % K;
    int t = i / (K * 8);
    o[i] = f2bf(d[((size_t)k * 8 + r) * 8 + t]);
}

__device__ __forceinline__ void do_prep_u(
    const float* __restrict__ u, u16* __restrict__ o, int F, int blk)
{
    int i = blk * 256 + (int)threadIdx.x;
    int r = i & 7;
    int f = (i >> 3) % F;
    int t = i / (F * 8);
    o[i] = f2bf(u[((size_t)r * F + f) * 8 + t] * 2.0f);
}

__global__ __launch_bounds__(256) void prep_all(
    const float* x, const float* k0, const float* k1, const float* k2,
    const float* d0, const float* d1, const float* d2,
    const float* u0, const float* u1, const float* u2,
    u16* xb, u16* k0T, u16* k1T, u16* k2T,
    u16* dS0, u16* dS1, u16* dS2, u16* uS0, u16* uS1, u16* uS2)
{
    int b = blockIdx.x;
    if      (b < 4096)  do_cvt(x, xb, b);
    else if (b < 6144)  do_transpose(k0, k0T, 1024, 2048, b - 4096);
    else if (b < 10240) do_transpose(k1, k1T, 2048, 2048, b - 6144);
    else if (b < 12288) do_transpose(k2, k2T, 2048, 1024, b - 10240);
    else if (b < 12544) do_prep_d(d0, dS0, 1024, b - 12288);
    else if (b < 13056) do_prep_d(d1, dS1, 2048, b - 12544);
    else if (b < 13568) do_prep_d(d2, dS2, 2048, b - 13056);
    else if (b < 14080) do_prep_u(u0, uS0, 2048, b - 13568);
    else if (b < 14592) do_prep_u(u1, uS1, 2048, b - 14080);
    else                do_prep_u(u2, uS2, 1024, b - 14592);
}

// ---------------- LoRA down-projection (unchanged) ----------------
__global__ __launch_bounds__(256) void lora_down(
    const u16* __restrict__ H, const u16* __restrict__ dS,
    u16* __restrict__ Aout, int K)
{
    int gt   = blockIdx.x * 256 + threadIdx.x;
    int row  = gt >> 3;
    int oct  = gt & 7;
    int task = row >> 10;
    const u16* hrow = H  + (size_t)row * K;
    const u16* dt   = dS + (size_t)task * K * 8;
    float acc[8];
#pragma unroll
    for (int r = 0; r < 8; ++r) acc[r] = 0.f;
    int kpt  = K >> 3;
    int kbeg = oct * kpt;
    for (int kk = kbeg; kk < kbeg + kpt; kk += 8) {
        u16x8 h8 = *(const u16x8*)(hrow + kk);
#pragma unroll
        for (int j = 0; j < 8; ++j) {
            float hv = bf2f(h8[j]);
            u16x8 dv = *(const u16x8*)(dt + (size_t)(kk + j) * 8);
#pragma unroll
            for (int r = 0; r < 8; ++r)
                acc[r] += hv * bf2f(dv[r]);
        }
    }
#pragma unroll
    for (int r = 0; r < 8; ++r) {
        acc[r] += __shfl_xor(acc[r], 1);
        acc[r] += __shfl_xor(acc[r], 2);
        acc[r] += __shfl_xor(acc[r], 4);
    }
    if (oct == 0) {
        u16x8 o;
#pragma unroll
        for (int r = 0; r < 8; ++r) o[r] = f2bf(acc[r]);
        *(u16x8*)(Aout + (size_t)row * 8) = o;
    }
}

// ============ 256xBN 8-phase GEMM + rank-8 LoRA epilogue ==================
// Swizzle (proven R3: 0 conflicts): logical 16B chunk kc of row r at slot
// kc^(r&7); stage via pre-swizzled global source; read slot=(ks*4+lg)^(l15&7).
//
// R6 scheduling change (m141/m97 lesson): NO manual lgkm walls, NO setprio.
// Phase = { STAGE issue ; plain ds_reads ; MFMAs } — the compiler interleaves
// reads and MFMAs with counted lgkmcnt (m97 evidence). One
// sched_barrier(0)+s_barrier per phase end: pins everything in-phase (so a
// phase-p ds_read can never sink past the phase-(p+2) STAGE that overwrites
// its slot), halves barrier count vs R5 (8/iter), and lets intra-phase
// LDS-read execution hide under MFMA.
//
// Hazard audit (1 barrier/phase):
//  - every phase's ds_reads are consumed by same-phase MFMAs -> compiler
//    waits them in-phase; sched_barrier pins them before the phase barrier.
//  - stage slot vs last reader: all slots have >=2 phase barriers between
//    the last reader's phase end and the overwriting STAGE issue (map below).
//  - stage readiness: vmcnt(C)@P3 retires exactly {prev-P6,prev-P7,P0,P1}
//    = the full buf1 tile, published by barrier(P3), first read at P4.
//    vmcnt(C)@P7 retires {P2..P5} = buf0 tile, first read next-iter P0.
//    C = loads of 2 phases kept in flight = 2+SBL (4 for BN=256, 3 for 128).
//  - slot map (iter i; t2=2i+2, t3=2i+3): P0 buf1.A1<-t1, P1 buf1.B1<-t1,
//    P2 buf0.A0<-t2, P3 buf0.B0<-t2, P4 buf0.A1<-t2, P5 buf0.B1<-t2,
//    P6 buf1.A0<-t3, P7 buf1.B0<-t3. Readers: buf0.{A0,B0}@P0, A1@P2(regs
//    reused P3), B1@P1(regs reused P3); buf1 mirrored at P4-P7.

#define WVMC do { if constexpr (BN == 256) { \
                    asm volatile("s_waitcnt vmcnt(4)" ::: "memory"); \
                  } else { \
                    asm volatile("s_waitcnt vmcnt(3)" ::: "memory"); } } while (0)
#define WVM0  asm volatile("s_waitcnt vmcnt(0)" ::: "memory")
#define PHASE_END do { __builtin_amdgcn_sched_barrier(0); \
                       __builtin_amdgcn_s_barrier(); } while (0)

#define DS_A(c, mh) do { \
    _Pragma("unroll") for (int mm = 0; mm < 4; ++mm) \
    _Pragma("unroll") for (int ks = 0; ks < 2; ++ks) \
        aF[mm][ks] = *(const bf16x8*)((const char*)&sA[c][0] + \
                       arowb + ((mh)*4+mm)*4096 + (ks ? cb1 : cb0)); } while (0)

#define DS_B(c, nh, bset) do { \
    _Pragma("unroll") for (int nn = 0; nn < NBH; ++nn) \
    _Pragma("unroll") for (int ks = 0; ks < 2; ++ks) \
        bset[nn][ks] = *(const bf16x8*)((const char*)&sB[c][0] + \
                       browb + ((nh)*NBH+nn)*8192 + (ks ? cb1 : cb0)); } while (0)

#define MFMAQ(mh, nh, bset) do { \
    _Pragma("unroll") for (int ks = 0; ks < 2; ++ks) \
    _Pragma("unroll") for (int mm = 0; mm < 4; ++mm) \
    _Pragma("unroll") for (int nn = 0; nn < NBH; ++nn) \
        acc[(mh)*4+mm][(nh)*NBH+nn] = __builtin_amdgcn_mfma_f32_16x16x32_bf16( \
            aF[mm][ks], bset[nn][ks], acc[(mh)*4+mm][(nh)*NBH+nn], 0, 0, 0); } while (0)

#define STAGE_A(c, h, kt) do { \
    _Pragma("unroll") for (int s = 0; s < 2; ++s) \
        gload_lds16((const char*)A + (size_t)(unsigned)(aBase + \
                      ((h)*128 + s*64)*(K*2) + (kt)*128), \
                    (char*)&sA[c][0] + (h)*16384 + s*8192 + tdst); } while (0)

#define STAGE_B(c, h, kt) do { \
    _Pragma("unroll") for (int s = 0; s < SBL; ++s) \
        gload_lds16((const char*)BT + (size_t)(unsigned)(bBase + \
                      ((h)*BNH + s*64)*(K*2) + (kt)*128), \
                    (char*)&sB[c][0] + (h)*(BNH*128) + s*8192 + tdst); } while (0)

template<int RELU, int BN, typename OUT_T>
__global__ __launch_bounds__(512, 2) void gemm_lora8(
    const u16* __restrict__ A, const u16* __restrict__ BT,
    const u16* __restrict__ ALR, const u16* __restrict__ US,
    const float* __restrict__ bias, OUT_T* __restrict__ C,
    int N, int K)
{
    constexpr int SBL = BN / 128;   // stage loads/thread per B-half
    constexpr int NBH = BN / 128;   // 16-col blocks per wave per B-half
    constexpr int NBN = BN / 64;    // 16-col blocks per wave total
    constexpr int BNH = BN / 2;     // rows per B-half

    __shared__ __align__(16) u16 sA[2][256 * 64];
    __shared__ __align__(16) u16 sB[2][BN * 64];

    const int tid  = threadIdx.x;
    const int lane = tid & 63;
    const int wave = tid >> 6;
    const int wr   = wave >> 2;   // 0..1
    const int wc   = wave & 3;    // 0..3
    const int l15  = lane & 15;
    const int lg   = lane >> 4;

    // bijective XCD swizzle (m204)
    const int nwg = gridDim.x;
    const int orig = blockIdx.x;
    const int q = nwg >> 3, r = nwg & 7;
    const int x = orig & 7, o = orig >> 3;
    const int wg = (x < r ? x * (q + 1) : r * (q + 1) + (x - r) * q) + o;
    const int nbn  = N / BN;
    const int bm   = wg / nbn;
    const int bn   = wg % nbn;
    const int brow = bm << 8;
    const int bcol = bn * BN;
    const int task = brow >> 10;

    // staging addressing (kc independent of h,s since half offsets are 0 mod 8)
    const int trow = tid >> 3;                       // 0..63
    const int tkc  = (tid & 7) ^ (trow & 7);
    const int tdst = tid * 16;
    const int aBase = (brow + trow) * (K * 2) + tkc * 16;
    const int bBase = (bcol + trow) * (K * 2) + tkc * 16;

    // ds_read column bases: slot = (ks*4+lg) ^ (l15&7)
    const int rp    = l15 & 7;
    const int cb0   = ((lg ^ (rp & 3)) << 4) | ((rp & 4) << 4);  // ks=0
    const int cb1   = cb0 ^ 64;                                   // ks=1
    const int arowb = (wr * 16 + l15) * 128;
    const int browb = (wc * 16 + l15) * 128;

    f32x4 acc[8][NBN];
    const f32x4 zf = {0.f, 0.f, 0.f, 0.f};
#pragma unroll
    for (int m = 0; m < 8; ++m)
#pragma unroll
        for (int n = 0; n < NBN; ++n) acc[m][n] = zf;

    bf16x8 aF[4][2], bF0[NBH][2], bF1[NBH][2];

    // prologue: buf0 <- t0 (4 halves), buf1 <- t1 A0,B0
    STAGE_A(0, 0, 0); STAGE_B(0, 0, 0); STAGE_A(0, 1, 0); STAGE_B(0, 1, 0);
    STAGE_A(1, 0, 1); STAGE_B(1, 0, 1);
    WVMC;              // buf0 tile landed; buf1 A0,B0 stay in flight
    PHASE_END;

    const int iters = K >> 7;
#pragma unroll 1
    for (int i = 0; i < iters; ++i) {
        const int t1 = 2 * i + 1, t2 = 2 * i + 2, t3 = 2 * i + 3;
        const bool nl = (i + 1 < iters);

        // P0: quad(0,0) buf0 ; stage buf1.A1 <- t1
        STAGE_A(1, 1, t1);
        DS_A(0, 0); DS_B(0, 0, bF0);
        MFMAQ(0, 0, bF0);
        PHASE_END;
        // P1: quad(0,1) buf0 ; stage buf1.B1 <- t1
        STAGE_B(1, 1, t1);
        DS_B(0, 1, bF1);
        MFMAQ(0, 1, bF1);
        PHASE_END;
        // P2: quad(1,0) buf0 ; stage buf0.A0 <- t2
        if (nl) STAGE_A(0, 0, t2);
        DS_A(0, 1);
        MFMAQ(1, 0, bF0);
        PHASE_END;
        // P3: quad(1,1) buf0 ; stage buf0.B0 <- t2 ; counted vmcnt
        if (nl) STAGE_B(0, 0, t2);
        MFMAQ(1, 1, bF1);
        if (nl) { WVMC; } else { WVM0; }
        PHASE_END;
        // P4: quad(0,0) buf1 ; stage buf0.A1 <- t2
        if (nl) STAGE_A(0, 1, t2);
        DS_A(1, 0); DS_B(1, 0, bF0);
        MFMAQ(0, 0, bF0);
        PHASE_END;
        // P5: quad(0,1) buf1 ; stage buf0.B1 <- t2
        if (nl) STAGE_B(0, 1, t2);
        DS_B(1, 1, bF1);
        MFMAQ(0, 1, bF1);
        PHASE_END;
        // P6: quad(1,0) buf1 ; stage buf1.A0 <- t3
        if (nl) STAGE_A(1, 0, t3);
        DS_A(1, 1);
        MFMAQ(1, 0, bF0);
        PHASE_END;
        // P7: quad(1,1) buf1 ; stage buf1.B0 <- t3 ; counted vmcnt
        if (nl) STAGE_B(1, 0, t3);
        MFMAQ(1, 1, bF1);
        if (nl) { WVMC; } else { WVM0; }
        PHASE_END;
    }

    // rank-8 LoRA delta: one extra MFMA round (k 0..7 valid, lanes lg>0 zero)
    bf16x8 z8 = zero_bf16x8();
    bf16x8 bU[NBN];
#pragma unroll
    for (int n = 0; n < NBN; ++n) {
        int col = bcol + n * 64 + wc * 16 + l15;
        bU[n] = (lg == 0) ? *(const bf16x8*)(US + ((size_t)task * N + col) * 8) : z8;
    }
#pragma unroll
    for (int m = 0; m < 8; ++m) {
        int row = brow + m * 32 + wr * 16 + l15;
        bf16x8 aL = (lg == 0) ? *(const bf16x8*)(ALR + (size_t)row * 8) : z8;
#pragma unroll
        for (int n = 0; n < NBN; ++n)
            acc[m][n] = __builtin_amdgcn_mfma_f32_16x16x32_bf16(
                aL, bU[n], acc[m][n], 0, 0, 0);
    }

    // bias (+ReLU) + store; C/D: col = lane&15, row = lg*4 + reg
#pragma unroll
    for (int n = 0; n < NBN; ++n) {
        int col  = bcol + n * 64 + wc * 16 + l15;
        float bv = bias[col];
#pragma unroll
        for (int m = 0; m < 8; ++m) {
            int row0 = brow + m * 32 + wr * 16 + lg * 4;
#pragma unroll
            for (int rr = 0; rr < 4; ++rr) {
                float v = acc[m][n][rr] + bv;
                if (RELU) v = fmaxf(v, 0.0f);
                store_out(&C[(size_t)(row0 + rr) * N + col], v);
            }
        }
    }
}

// ---------------- launch ----------------

extern "C" void kernel_launch(void* const* d_in, const int* in_sizes, int n_in,
                              void* d_out, int out_size, void* d_ws, size_t ws_size,
                              hipStream_t stream) {
    const float* x  = (const float*)d_in[0];
    const float* k0 = (const float*)d_in[1];
    const float* b0 = (const float*)d_in[2];
    const float* d0 = (const float*)d_in[3];
    const float* u0 = (const float*)d_in[4];
    const float* k1 = (const float*)d_in[5];
    const float* b1 = (const float*)d_in[6];
    const float* d1 = (const float*)d_in[7];
    const float* u1 = (const float*)d_in[8];
    const float* k2 = (const float*)d_in[9];
    const float* b2 = (const float*)d_in[10];
    const float* d2 = (const float*)d_in[11];
    const float* u2 = (const float*)d_in[12];

    const int T = 8, B = 1024, D = 1024, H1 = 2048, H2 = 2048, H3 = 1024;
    const int M = T * B;

    u16* w = (u16*)d_ws;
    size_t off = 0;
    u16* xb  = w + off; off += (size_t)M * D;
    u16* k0T = w + off; off += (size_t)H1 * D;
    u16* k1T = w + off; off += (size_t)H2 * H1;
    u16* k2T = w + off; off += (size_t)H3 * H2;
    u16* dS0 = w + off; off += (size_t)T * D * 8;
    u16* dS1 = w + off; off += (size_t)T * H1 * 8;
    u16* dS2 = w + off; off += (size_t)T * H2 * 8;
    u16* uS0 = w + off; off += (size_t)T * H1 * 8;
    u16* uS1 = w + off; off += (size_t)T * H2 * 8;
    u16* uS2 = w + off; off += (size_t)T * H3 * 8;
    u16* h1  = w + off; off += (size_t)M * H1;
    u16* h2  = w + off; off += (size_t)M * H2;
    u16* Ab  = w + off; off += (size_t)M * 8;
    (void)ws_size; (void)in_sizes; (void)n_in; (void)out_size;

    prep_all<<<14848, 256, 0, stream>>>(
        x, k0, k1, k2, d0, d1, d2, u0, u1, u2,
        xb, k0T, k1T, k2T, dS0, dS1, dS2, uS0, uS1, uS2);

    // layer 0 (BN=256: 32x8 = 256 blocks)
    lora_down<<<(M * 8) / 256, 256, 0, stream>>>(xb, dS0, Ab, D);
    gemm_lora8<1, 256, u16><<<(M / 256) * (H1 / 256), 512, 0, stream>>>(
        xb, k0T, Ab, uS0, b0, h1, H1, D);
    // layer 1 (BN=256: 32x8 = 256 blocks)
    lora_down<<<(M * 8) / 256, 256, 0, stream>>>(h1, dS1, Ab, H1);
    gemm_lora8<1, 256, u16><<<(M / 256) * (H2 / 256), 512, 0, stream>>>(
        h1, k1T, Ab, uS1, b1, h2, H2, H1);
    // layer 2 (no relu, fp32 out; BN=128: 32x8 = 256 blocks, full grid)
    lora_down<<<(M * 8) / 256, 256, 0, stream>>>(h2, dS2, Ab, H2);
    gemm_lora8<0, 128, float><<<(M / 256) * (H3 / 128), 512, 0, stream>>>(
        h2, k2T, Ab, uS2, b2, (float*)d_out, H3, H2);
}